// Round 4
// baseline (412.968 us; speedup 1.0000x reference)
//
#include <hip/hip_runtime.h>
#include <math.h>

#define B_    2
#define C_    64
#define N_    20000
#define K_    16
#define COUT_ 64
#define TN1   64
#define NB1   ((N_ + TN1 - 1) / TN1)   // 313
#define TN2   32
#define NB2   ((N_ + TN2 - 1) / TN2)   // 625

static __device__ __forceinline__ unsigned short f2bf(float f) {
    union { float f; unsigned u; } v; v.f = f;
    unsigned r = (v.u + 0x7FFFu + ((v.u >> 16) & 1u)) >> 16;  // RNE
    return (unsigned short)r;
}

// ---------------------------------------------------------------------------
// Stage 1: z = (W1-W2)x + b, y = W2 x, stored bf16 in [b][n][64ch] rows
// (128 B/node/table -> full-cache-line gathers in stage 2), plus edge prep
// (packed indices + fp32 suppression).
// Weights live in LDS (NOT per-lane registers -- the round-3 version spilled:
// VGPR=128, ~80 MB scratch traffic). lane = o; padded LDS rows make the
// per-lane b128 weight reads 2-way/bank = conflict-free.
// ---------------------------------------------------------------------------
__global__ __launch_bounds__(256, 3)
void stage1(const float* __restrict__ x, const int* __restrict__ ei,
            const float* __restrict__ pos, const float* __restrict__ W,
            const float* __restrict__ bias,
            unsigned short* __restrict__ zbuf, unsigned short* __restrict__ ybuf,
            unsigned int* __restrict__ pk, float* __restrict__ sup) {
    __shared__ float xt [TN1][68];   // x tile transposed [n][c]
    __shared__ float wzl[64][68];    // W1-W2, [o][c]
    __shared__ float wyl[64][68];    // W2,    [o][c]

    const int bi   = blockIdx.x;
    const int b    = bi / NB1;
    const int n0   = (bi % NB1) * TN1;
    const int t    = threadIdx.x;
    const int lane = t & 63;         // = output channel o
    const int w    = t >> 6;

    // ---- stage weights into LDS (coalesced global reads) ----
    #pragma unroll
    for (int r = 0; r < 16; ++r) {
        int flat = r * 256 + t;      // 4096 = 64o x 64c
        int o = flat >> 6, c = flat & 63;
        float w1 = W[o * 128 + c];
        float w2 = W[o * 128 + 64 + c];
        wzl[o][c] = w1 - w2;
        wyl[o][c] = w2;
    }

    // ---- stage x tile transposed (coalesced global reads) ----
    const float* xb = x + (size_t)b * C_ * N_;
    #pragma unroll
    for (int r = 0; r < 16; ++r) {
        int flat = r * 256 + t;      // 4096 = 64c x 64n
        int c = flat >> 6, nl = flat & 63;
        int n = n0 + nl;
        xt[nl][c] = (n < N_) ? xb[c * N_ + n] : 0.0f;
    }

    const float bo = bias[lane];
    __syncthreads();

    // ---- wave w computes nodes [w*16, w*16+16) in two 8-node batches ----
    #pragma unroll 1
    for (int sb = 0; sb < 2; ++sb) {
        const int nb = w * 16 + sb * 8;
        float zz[8], yy[8];
        #pragma unroll
        for (int i = 0; i < 8; ++i) { zz[i] = bo; yy[i] = 0.0f; }
        #pragma unroll
        for (int c4 = 0; c4 < 16; ++c4) {
            float4 wzv = *(const float4*)&wzl[lane][c4 * 4];  // b128, conflict-free
            float4 wyv = *(const float4*)&wyl[lane][c4 * 4];
            #pragma unroll
            for (int i = 0; i < 8; ++i) {
                float4 xv = *(const float4*)&xt[nb + i][c4 * 4];  // broadcast
                zz[i] = fmaf(wzv.x, xv.x, zz[i]);  yy[i] = fmaf(wyv.x, xv.x, yy[i]);
                zz[i] = fmaf(wzv.y, xv.y, zz[i]);  yy[i] = fmaf(wyv.y, xv.y, yy[i]);
                zz[i] = fmaf(wzv.z, xv.z, zz[i]);  yy[i] = fmaf(wyv.z, xv.z, yy[i]);
                zz[i] = fmaf(wzv.w, xv.w, zz[i]);  yy[i] = fmaf(wyv.w, xv.w, yy[i]);
            }
        }
        #pragma unroll
        for (int i = 0; i < 8; ++i) {
            int n = n0 + nb + i;
            if (n < N_) {
                size_t off = ((size_t)b * N_ + n) * 64 + lane;  // 128B/row, coalesced
                zbuf[off] = f2bf(zz[i]);
                ybuf[off] = f2bf(yy[i]);
            }
        }
    }

    // ---- edge prep: 1024 edges for this tile ----
    const int*   e0 = ei + (size_t)b * N_ * K_;
    const int*   e1 = ei + ((size_t)B_ + b) * N_ * K_;
    const float* pb = pos + (size_t)b * 3 * N_;
    #pragma unroll
    for (int i = 0; i < 4; ++i) {
        int idx = n0 * K_ + i * 256 + t;            // coalesced
        if (idx < N_ * K_) {
            int i0 = e0[idx];
            int i1 = e1[idx];
            float dx = pb[i0]        - pb[i1];
            float dy = pb[N_ + i0]   - pb[N_ + i1];
            float dz = pb[2*N_ + i0] - pb[2*N_ + i1];
            float dis = sqrtf(dx*dx + dy*dy + dz*dz);
            float s = 2.0f / (1.0f + __expf(dis));  // 2*sigmoid(-dis)
            pk [(size_t)b * N_ * K_ + idx] = (unsigned)i0 | ((unsigned)i1 << 16);
            sup[(size_t)b * N_ * K_ + idx] = s;
        }
    }
}

// ---------------------------------------------------------------------------
// Stage 2: out[b][o][n] = max_k relu(z[i1][o] + y[i0][o]) * s_k.
// lane = (node-half nh, ch-pair cp): per k, each lane does two ushort2 bf16
// gathers (z @ i1, y @ i0) -> per edge 2 full 128 B rows, 100% line
// utilization. 16-deep unrolled k-loop = 32+ independent loads in flight.
// 1250 blocks (~20 waves/CU) for latency hiding.
// ---------------------------------------------------------------------------
__global__ __launch_bounds__(256, 4)
void stage2(const unsigned int* __restrict__ pk, const float* __restrict__ sup,
            const unsigned short* __restrict__ zbuf,
            const unsigned short* __restrict__ ybuf,
            float* __restrict__ out) {
    __shared__ float tile[64][TN2 + 1];  // [o][n_local], 8.4 KB

    const int bi   = blockIdx.x;
    const int b    = bi / NB2;
    const int n0   = (bi % NB2) * TN2;
    const int t    = threadIdx.x;
    const int lane = t & 63;
    const int w    = t >> 6;
    const int nh   = lane >> 5;          // node half 0/1
    const int cp   = lane & 31;          // channel pair 0..31

    const unsigned int*   pkb  = pk  + (size_t)b * N_ * K_;
    const float*          supb = sup + (size_t)b * N_ * K_;
    const unsigned short* zb   = zbuf + (size_t)b * N_ * 64;
    const unsigned short* yb   = ybuf + (size_t)b * N_ * 64;

    #pragma unroll 1
    for (int j = 0; j < 4; ++j) {
        int nl = w * 8 + j * 2 + nh;     // 0..31 within tile
        int n  = n0 + nl;
        float v0 = 0.0f, v1 = 0.0f;      // relu(..)*s >= 0 -> 0 is valid identity
        if (n < N_) {
            const unsigned int* pkr = pkb  + (size_t)n * K_;
            const float*        sur = supb + (size_t)n * K_;
            #pragma unroll
            for (int k = 0; k < 16; ++k) {
                unsigned p  = pkr[k];    // half-wave-uniform -> 1 tx
                float    sk = sur[k];
                int i0 = (int)(p & 0xFFFFu);
                int i1 = (int)(p >> 16);
                unsigned z2 = *(const unsigned int*)(zb + (size_t)i1 * 64 + cp * 2);
                unsigned y2 = *(const unsigned int*)(yb + (size_t)i0 * 64 + cp * 2);
                union { unsigned u; float f; } za, zc, ya, yc;
                za.u = z2 << 16;  zc.u = z2 & 0xFFFF0000u;
                ya.u = y2 << 16;  yc.u = y2 & 0xFFFF0000u;
                v0 = fmaxf(v0, fmaxf(za.f + ya.f, 0.0f) * sk);
                v1 = fmaxf(v1, fmaxf(zc.f + yc.f, 0.0f) * sk);
            }
        }
        tile[2 * cp    ][nl] = v0;
        tile[2 * cp + 1][nl] = v1;
    }

    __syncthreads();

    // coalesced writeback: 64 ch x 32 nodes
    #pragma unroll
    for (int r = 0; r < 8; ++r) {
        int flat = r * 256 + t;          // 2048 = 64o x 32n
        int o  = flat >> 5;
        int nl = flat & 31;
        int n  = n0 + nl;
        if (n < N_) out[((size_t)b * COUT_ + o) * N_ + n] = tile[o][nl];
    }
}

// ---------------------------------------------------------------------------
extern "C" void kernel_launch(void* const* d_in, const int* in_sizes, int n_in,
                              void* d_out, int out_size, void* d_ws, size_t ws_size,
                              hipStream_t stream) {
    const float* x    = (const float*)d_in[0];   // [B, C, N, 1]
    const int*   ei   = (const int*)  d_in[1];   // [2, B, N, K]
    const float* pos  = (const float*)d_in[2];   // [B, 3, N, 1]
    const float* W    = (const float*)d_in[3];   // [COUT, 2C]
    const float* bias = (const float*)d_in[4];   // [COUT]
    float*       out  = (float*)d_out;           // [B, COUT, N, 1]

    const size_t tabElems = (size_t)B_ * N_ * 64;            // 2.56M ushorts
    unsigned short* zbuf = (unsigned short*)d_ws;
    unsigned short* ybuf = zbuf + tabElems;
    unsigned int*   pk   = (unsigned int*)(ybuf + tabElems); // 4B-aligned
    float*          sup  = (float*)(pk + (size_t)B_ * N_ * K_);

    hipLaunchKernelGGL(stage1, dim3(B_ * NB1), dim3(256), 0, stream,
                       x, ei, pos, W, bias, zbuf, ybuf, pk, sup);
    hipLaunchKernelGGL(stage2, dim3(B_ * NB2), dim3(256), 0, stream,
                       pk, sup, zbuf, ybuf, out);
}

// Round 5
// 112.654 us; speedup vs baseline: 3.6658x; 3.6658x over previous
//
#include <hip/hip_runtime.h>
#include <math.h>

#define B_    2
#define C_    64
#define N_    20000
#define K_    16
#define COUT_ 64
#define TN1   64
#define NB1   ((N_ + TN1 - 1) / TN1)   // 313
#define TN2   32
#define NB2   (N_ / TN2)               // 625 (exact, no tail)

typedef unsigned int   u32;
typedef unsigned short u16;

static __device__ __forceinline__ u16 f2bf(float f) {
    union { float f; u32 u; } v; v.f = f;
    u32 r = (v.u + 0x7FFFu + ((v.u >> 16) & 1u)) >> 16;  // RNE
    return (u16)r;
}
static __device__ __forceinline__ float uasf(u32 u) {
    union { u32 u; float f; } v; v.u = u; return v.f;
}

// ---------------------------------------------------------------------------
// Stage 1: z = (W1-W2)x + b, y = W2 x  -> bf16 tables [b][n][64ch] (128 B
// rows), plus edge prep packed as uint2(indices, suppression).
// SCRATCH-PROOF: weights live in LDS [c][(wz,wy)] (per-lane float2 read,
// conflict-free); accumulators are 8 NAMED float4s. No per-thread arrays --
// rounds 3/4 proved LLVM demotes them to scratch (330 us, 564 MB writes).
// ---------------------------------------------------------------------------
__global__ __launch_bounds__(256)
void stage1(const float* __restrict__ x, const int* __restrict__ ei,
            const float* __restrict__ pos, const float* __restrict__ W,
            const float* __restrict__ bias,
            u16* __restrict__ zbuf, u16* __restrict__ ybuf,
            uint2* __restrict__ es) {
    __shared__ float xt[64][68];    // [c][n_local], rows 16B-aligned
    __shared__ float wc[64][130];   // [c][2*o+{0,1}] = (w1-w2, w2)

    const int bi   = blockIdx.x;
    const int b    = bi / NB1;
    const int n0   = (bi % NB1) * TN1;
    const int t    = threadIdx.x;
    const int lane = t & 63;        // = output channel o
    const int w    = t >> 6;

    // ---- stage weights (coalesced): 64o x 64c ----
    #pragma unroll
    for (int r = 0; r < 16; ++r) {
        int flat = r * 256 + t;
        int o = flat >> 6, c = flat & 63;
        float w1 = W[o * 128 + c];
        float w2 = W[o * 128 + 64 + c];
        wc[c][2 * o]     = w1 - w2;
        wc[c][2 * o + 1] = w2;
    }
    // ---- stage x tile [c][n] via float4 (coalesced) ----
    const float* xb = x + (size_t)b * C_ * N_;
    #pragma unroll
    for (int r = 0; r < 4; ++r) {
        int flat = r * 256 + t;
        int c = flat >> 4, ng = (flat & 15) * 4;
        int n = n0 + ng;
        float4 v;
        if (n + 3 < N_) {
            v = *(const float4*)&xb[c * N_ + n];
        } else {
            v.x = (n     < N_) ? xb[c * N_ + n    ] : 0.0f;
            v.y = (n + 1 < N_) ? xb[c * N_ + n + 1] : 0.0f;
            v.z = (n + 2 < N_) ? xb[c * N_ + n + 2] : 0.0f;
            v.w = (n + 3 < N_) ? xb[c * N_ + n + 3] : 0.0f;
        }
        *(float4*)&xt[c][ng] = v;
    }
    const float bo = bias[lane];
    __syncthreads();

    // ---- wave computes 16 nodes, all accumulators NAMED float4 ----
    const int nb = w * 16;
    float4 z0 = {bo,bo,bo,bo}, z1 = z0, z2 = z0, z3 = z0;
    float4 y0 = {0,0,0,0},     y1 = y0, y2 = y0, y3 = y0;

#define FMA4(ZR, YR, XV) \
    ZR.x = fmaf(wv.x, XV.x, ZR.x);  YR.x = fmaf(wv.y, XV.x, YR.x); \
    ZR.y = fmaf(wv.x, XV.y, ZR.y);  YR.y = fmaf(wv.y, XV.y, YR.y); \
    ZR.z = fmaf(wv.x, XV.z, ZR.z);  YR.z = fmaf(wv.y, XV.z, YR.z); \
    ZR.w = fmaf(wv.x, XV.w, ZR.w);  YR.w = fmaf(wv.y, XV.w, YR.w);

    #pragma unroll 2
    for (int c = 0; c < 64; ++c) {
        float2 wv = *(const float2*)&wc[c][2 * lane];   // conflict-free
        float4 xa = *(const float4*)&xt[c][nb];         // uniform broadcasts
        float4 xv1 = *(const float4*)&xt[c][nb + 4];
        float4 xv2 = *(const float4*)&xt[c][nb + 8];
        float4 xv3 = *(const float4*)&xt[c][nb + 12];
        FMA4(z0, y0, xa)
        FMA4(z1, y1, xv1)
        FMA4(z2, y2, xv2)
        FMA4(z3, y3, xv3)
    }
#undef FMA4

    {
        const size_t rowb = (size_t)b * N_;
        auto st = [&](int i, float zv, float yv) {
            int n = n0 + nb + i;
            if (n < N_) {
                size_t off = (rowb + n) * 64 + lane;    // 128 B coalesced
                zbuf[off] = f2bf(zv);
                ybuf[off] = f2bf(yv);
            }
        };
        st(0,  z0.x, y0.x); st(1,  z0.y, y0.y); st(2,  z0.z, y0.z); st(3,  z0.w, y0.w);
        st(4,  z1.x, y1.x); st(5,  z1.y, y1.y); st(6,  z1.z, y1.z); st(7,  z1.w, y1.w);
        st(8,  z2.x, y2.x); st(9,  z2.y, y2.y); st(10, z2.z, y2.z); st(11, z2.w, y2.w);
        st(12, z3.x, y3.x); st(13, z3.y, y3.y); st(14, z3.z, y3.z); st(15, z3.w, y3.w);
    }

    // ---- edge prep: pack (i0,i1) + fp32 suppression into one uint2 ----
    const int*   e0 = ei + (size_t)b * N_ * K_;
    const int*   e1 = ei + ((size_t)B_ + b) * N_ * K_;
    const float* pb = pos + (size_t)b * 3 * N_;
    uint2* esb = es + (size_t)b * N_ * K_;
    #pragma unroll
    for (int i = 0; i < 4; ++i) {
        int idx = n0 * K_ + i * 256 + t;     // coalesced
        if (idx < N_ * K_) {
            int i0 = e0[idx], i1 = e1[idx];
            float dx = pb[i0]          - pb[i1];
            float dy = pb[N_ + i0]     - pb[N_ + i1];
            float dz = pb[2 * N_ + i0] - pb[2 * N_ + i1];
            float dis = sqrtf(dx * dx + dy * dy + dz * dz);
            float s = 2.0f / (1.0f + __expf(dis));      // 2*sigmoid(-dis)
            esb[idx] = make_uint2((u32)i0 | ((u32)i1 << 16), __float_as_uint(s));
        }
    }
}

// ---------------------------------------------------------------------------
// Stage 2: out[b][o][n] = max_k relu(z[i1][o] + y[i0][o]) * s_k.
// lane = (node-octet n8, 16B-chunk cq): ONE dwordx4 instruction gathers 8
// edges' z-rows (8x fewer mem instrs than round 4). No cross-lane reduce:
// each lane accumulates the max for its (node, 8 channels) in 2 named
// float4s. pk+sup prefetched into padded LDS. 1250 blocks, no tail.
// ---------------------------------------------------------------------------
__global__ __launch_bounds__(256)
void stage2(const uint2* __restrict__ es,
            const u16* __restrict__ zbuf, const u16* __restrict__ ybuf,
            float* __restrict__ out) {
    __shared__ uint2 esl[TN2][17];       // pad 17 -> conflict-free octet reads
    __shared__ float tile[TN2][66];      // [n_local][o], pad 66

    const int bi   = blockIdx.x;
    const int b    = bi / NB2;
    const int n0   = (bi % NB2) * TN2;
    const int t    = threadIdx.x;
    const int lane = t & 63;
    const int w    = t >> 6;
    const int n8   = lane >> 3;          // node within octet group 0..7
    const int cq   = lane & 7;           // 16B chunk = 8 channels

    // ---- prefetch this tile's 512 uint2 edge records ----
    const uint2* esb = es + (size_t)b * N_ * K_ + (size_t)n0 * K_;
    #pragma unroll
    for (int r = 0; r < 2; ++r) {
        int idx = r * 256 + t;
        esl[idx >> 4][idx & 15] = esb[idx];   // coalesced global read
    }
    __syncthreads();

    const u16* zb = zbuf + (size_t)b * N_ * 64;
    const u16* yb = ybuf + (size_t)b * N_ * 64;
    const int  nl = w * 8 + n8;          // this lane's node 0..31

    float4 ma = {0,0,0,0}, mb = {0,0,0,0};   // 8 channel maxima (named)

#define COMB(ZW, YW, MLO, MHI) { \
    float zl = uasf((ZW) << 16), zh = uasf((ZW) & 0xFFFF0000u); \
    float yl = uasf((YW) << 16), yh = uasf((YW) & 0xFFFF0000u); \
    MLO = fmaxf(MLO, fmaxf(zl + yl, 0.0f) * s); \
    MHI = fmaxf(MHI, fmaxf(zh + yh, 0.0f) * s); }

    #pragma unroll 4
    for (int k = 0; k < K_; ++k) {
        uint2 e = esl[nl][k];            // octet-broadcast, conflict-free
        int   i0 = (int)(e.x & 0xFFFFu);
        int   i1 = (int)(e.x >> 16);
        float s  = uasf(e.y);
        uint4 z4 = *((const uint4*)(zb + ((size_t)i1 << 6)) + cq);  // 16 B
        uint4 y4 = *((const uint4*)(yb + ((size_t)i0 << 6)) + cq);
        COMB(z4.x, y4.x, ma.x, ma.y)
        COMB(z4.y, y4.y, ma.z, ma.w)
        COMB(z4.z, y4.z, mb.x, mb.y)
        COMB(z4.w, y4.w, mb.z, mb.w)
    }
#undef COMB

    // ---- park results in LDS [n][o] (float2 writes, mild 4-way ok) ----
    {
        int cb = cq * 8;
        *(float2*)&tile[nl][cb]     = make_float2(ma.x, ma.y);
        *(float2*)&tile[nl][cb + 2] = make_float2(ma.z, ma.w);
        *(float2*)&tile[nl][cb + 4] = make_float2(mb.x, mb.y);
        *(float2*)&tile[nl][cb + 6] = make_float2(mb.z, mb.w);
    }
    __syncthreads();

    // ---- coalesced writeback: 64 o x 32 n ----
    #pragma unroll
    for (int r = 0; r < 8; ++r) {
        int flat = r * 256 + t;
        int o = flat >> 5, n2 = flat & 31;
        out[((size_t)b * COUT_ + o) * N_ + n0 + n2] = tile[n2][o];
    }
}

// ---------------------------------------------------------------------------
extern "C" void kernel_launch(void* const* d_in, const int* in_sizes, int n_in,
                              void* d_out, int out_size, void* d_ws, size_t ws_size,
                              hipStream_t stream) {
    const float* x    = (const float*)d_in[0];   // [B, C, N, 1]
    const int*   ei   = (const int*)  d_in[1];   // [2, B, N, K]
    const float* pos  = (const float*)d_in[2];   // [B, 3, N, 1]
    const float* W    = (const float*)d_in[3];   // [COUT, 2C]
    const float* bias = (const float*)d_in[4];   // [COUT]
    float*       out  = (float*)d_out;           // [B, COUT, N, 1]

    const size_t tabElems = (size_t)B_ * N_ * 64;            // 2.56M u16
    u16*   zbuf = (u16*)d_ws;                                // 5.12 MB
    u16*   ybuf = zbuf + tabElems;                           // 5.12 MB
    uint2* es   = (uint2*)(ybuf + tabElems);                 // 5.12 MB, 8B-aligned

    hipLaunchKernelGGL(stage1, dim3(B_ * NB1), dim3(256), 0, stream,
                       x, ei, pos, W, bias, zbuf, ybuf, es);
    hipLaunchKernelGGL(stage2, dim3(B_ * NB2), dim3(256), 0, stream,
                       es, zbuf, ybuf, out);
}

// Round 6
// 112.183 us; speedup vs baseline: 3.6812x; 1.0042x over previous
//
#include <hip/hip_runtime.h>
#include <math.h>

#define B_    2
#define C_    64
#define N_    20000
#define K_    16
#define COUT_ 64
#define TN1   64
#define NB1   ((N_ + TN1 - 1) / TN1)   // 313
#define TN2   16
#define NB2   (N_ / TN2)               // 1250 (exact, no tail)

typedef unsigned int   u32;
typedef unsigned short u16;

static __device__ __forceinline__ u16 f2bf(float f) {
    union { float f; u32 u; } v; v.f = f;
    u32 r = (v.u + 0x7FFFu + ((v.u >> 16) & 1u)) >> 16;  // RNE
    return (u16)r;
}
static __device__ __forceinline__ float uasf(u32 u) {
    union { u32 u; float f; } v; v.u = u; return v.f;
}

// ---------------------------------------------------------------------------
// Stage 1: z = (W1-W2)x + b, y = W2 x  -> bf16 tables [b][n][64ch] (128 B
// rows), plus edge prep packed as uint2(indices, suppression).
// SCRATCH-PROOF: weights live in LDS [c][(wz,wy)] (per-lane float2 read,
// conflict-free); accumulators are 8 NAMED float4s. No per-thread arrays --
// rounds 3/4 proved LLVM demotes them to scratch (330 us, 564 MB writes).
// ---------------------------------------------------------------------------
__global__ __launch_bounds__(256)
void stage1(const float* __restrict__ x, const int* __restrict__ ei,
            const float* __restrict__ pos, const float* __restrict__ W,
            const float* __restrict__ bias,
            u16* __restrict__ zbuf, u16* __restrict__ ybuf,
            uint2* __restrict__ es) {
    __shared__ float xt[64][68];    // [c][n_local], rows 16B-aligned
    __shared__ float wc[64][130];   // [c][2*o+{0,1}] = (w1-w2, w2)

    const int bi   = blockIdx.x;
    const int b    = bi / NB1;
    const int n0   = (bi % NB1) * TN1;
    const int t    = threadIdx.x;
    const int lane = t & 63;        // = output channel o
    const int w    = t >> 6;

    // ---- stage weights (coalesced): 64o x 64c ----
    #pragma unroll
    for (int r = 0; r < 16; ++r) {
        int flat = r * 256 + t;
        int o = flat >> 6, c = flat & 63;
        float w1 = W[o * 128 + c];
        float w2 = W[o * 128 + 64 + c];
        wc[c][2 * o]     = w1 - w2;
        wc[c][2 * o + 1] = w2;
    }
    // ---- stage x tile [c][n] via float4 (coalesced) ----
    const float* xb = x + (size_t)b * C_ * N_;
    #pragma unroll
    for (int r = 0; r < 4; ++r) {
        int flat = r * 256 + t;
        int c = flat >> 4, ng = (flat & 15) * 4;
        int n = n0 + ng;
        float4 v;
        if (n + 3 < N_) {
            v = *(const float4*)&xb[c * N_ + n];
        } else {
            v.x = (n     < N_) ? xb[c * N_ + n    ] : 0.0f;
            v.y = (n + 1 < N_) ? xb[c * N_ + n + 1] : 0.0f;
            v.z = (n + 2 < N_) ? xb[c * N_ + n + 2] : 0.0f;
            v.w = (n + 3 < N_) ? xb[c * N_ + n + 3] : 0.0f;
        }
        *(float4*)&xt[c][ng] = v;
    }
    const float bo = bias[lane];
    __syncthreads();

    // ---- wave computes 16 nodes, all accumulators NAMED float4 ----
    const int nb = w * 16;
    float4 z0 = {bo,bo,bo,bo}, z1 = z0, z2 = z0, z3 = z0;
    float4 y0 = {0,0,0,0},     y1 = y0, y2 = y0, y3 = y0;

#define FMA4(ZR, YR, XV) \
    ZR.x = fmaf(wv.x, XV.x, ZR.x);  YR.x = fmaf(wv.y, XV.x, YR.x); \
    ZR.y = fmaf(wv.x, XV.y, ZR.y);  YR.y = fmaf(wv.y, XV.y, YR.y); \
    ZR.z = fmaf(wv.x, XV.z, ZR.z);  YR.z = fmaf(wv.y, XV.z, YR.z); \
    ZR.w = fmaf(wv.x, XV.w, ZR.w);  YR.w = fmaf(wv.y, XV.w, YR.w);

    #pragma unroll 2
    for (int c = 0; c < 64; ++c) {
        float2 wv = *(const float2*)&wc[c][2 * lane];   // conflict-free
        float4 xa = *(const float4*)&xt[c][nb];         // uniform broadcasts
        float4 xv1 = *(const float4*)&xt[c][nb + 4];
        float4 xv2 = *(const float4*)&xt[c][nb + 8];
        float4 xv3 = *(const float4*)&xt[c][nb + 12];
        FMA4(z0, y0, xa)
        FMA4(z1, y1, xv1)
        FMA4(z2, y2, xv2)
        FMA4(z3, y3, xv3)
    }
#undef FMA4

    {
        const size_t rowb = (size_t)b * N_;
        auto st = [&](int i, float zv, float yv) {
            int n = n0 + nb + i;
            if (n < N_) {
                size_t off = (rowb + n) * 64 + lane;    // 128 B coalesced
                zbuf[off] = f2bf(zv);
                ybuf[off] = f2bf(yv);
            }
        };
        st(0,  z0.x, y0.x); st(1,  z0.y, y0.y); st(2,  z0.z, y0.z); st(3,  z0.w, y0.w);
        st(4,  z1.x, y1.x); st(5,  z1.y, y1.y); st(6,  z1.z, y1.z); st(7,  z1.w, y1.w);
        st(8,  z2.x, y2.x); st(9,  z2.y, y2.y); st(10, z2.z, y2.z); st(11, z2.w, y2.w);
        st(12, z3.x, y3.x); st(13, z3.y, y3.y); st(14, z3.z, y3.z); st(15, z3.w, y3.w);
    }

    // ---- edge prep: pack (i0,i1) + fp32 suppression into one uint2 ----
    const int*   e0 = ei + (size_t)b * N_ * K_;
    const int*   e1 = ei + ((size_t)B_ + b) * N_ * K_;
    const float* pb = pos + (size_t)b * 3 * N_;
    uint2* esb = es + (size_t)b * N_ * K_;
    #pragma unroll
    for (int i = 0; i < 4; ++i) {
        int idx = n0 * K_ + i * 256 + t;     // coalesced
        if (idx < N_ * K_) {
            int i0 = e0[idx], i1 = e1[idx];
            float dx = pb[i0]          - pb[i1];
            float dy = pb[N_ + i0]     - pb[N_ + i1];
            float dz = pb[2 * N_ + i0] - pb[2 * N_ + i1];
            float dis = sqrtf(dx * dx + dy * dy + dz * dz);
            float s = 2.0f / (1.0f + __expf(dis));      // 2*sigmoid(-dis)
            esb[idx] = make_uint2((u32)i0 | ((u32)i1 << 16), __float_as_uint(s));
        }
    }
}

// ---------------------------------------------------------------------------
// Stage 2: out[b][o][n] = max_k relu(z[i1][o] + y[i0][o]) * s_k.
// MLP-maximized: lane = (node nl = t>>4, k-parity kh, 16B chunk cq). Each
// lane owns 8 of the 16 k's, FULLY unrolled -> up to 16 b128 gathers in
// flight (2x round 5); one shfl_xor(8)+max merges the two parities.
// TN2=16 -> 2500 blocks (~8 blocks/CU resident) for wave-level MLP.
// ---------------------------------------------------------------------------
__global__ __launch_bounds__(256)
void stage2(const uint2* __restrict__ es,
            const u16* __restrict__ zbuf, const u16* __restrict__ ybuf,
            float* __restrict__ out) {
    __shared__ uint2 esl[TN2][17];       // pad 17 -> low-conflict reads
    __shared__ float tile[TN2][66];      // [n_local][o]

    const int bi   = blockIdx.x;
    const int b    = bi / NB2;
    const int n0   = (bi % NB2) * TN2;
    const int t    = threadIdx.x;
    const int nl   = t >> 4;             // node 0..15
    const int kh   = (t >> 3) & 1;       // k parity 0/1
    const int cq   = t & 7;              // 16B chunk = 8 channels

    // ---- prefetch this tile's 256 uint2 edge records ----
    const uint2* esb = es + (size_t)b * N_ * K_ + (size_t)n0 * K_;
    esl[t >> 4][t & 15] = esb[t];        // coalesced
    __syncthreads();

    const u16* zb = zbuf + (size_t)b * N_ * 64;
    const u16* yb = ybuf + (size_t)b * N_ * 64;

    float4 ma = {0,0,0,0}, mb = {0,0,0,0};   // 8 channel maxima (named)

#define COMB(ZW, YW, MLO, MHI) { \
    float zl = uasf((ZW) << 16), zh = uasf((ZW) & 0xFFFF0000u); \
    float yl = uasf((YW) << 16), yh = uasf((YW) & 0xFFFF0000u); \
    MLO = fmaxf(MLO, fmaxf(zl + yl, 0.0f) * s); \
    MHI = fmaxf(MHI, fmaxf(zh + yh, 0.0f) * s); }

    #pragma unroll
    for (int i = 0; i < 8; ++i) {
        int   k = 2 * i + kh;
        uint2 e = esl[nl][k];            // 8-lane broadcast
        int   i0 = (int)(e.x & 0xFFFFu);
        int   i1 = (int)(e.x >> 16);
        float s  = uasf(e.y);
        uint4 z4 = *((const uint4*)(zb + ((size_t)i1 << 6)) + cq);  // 16 B
        uint4 y4 = *((const uint4*)(yb + ((size_t)i0 << 6)) + cq);
        COMB(z4.x, y4.x, ma.x, ma.y)
        COMB(z4.y, y4.y, ma.z, ma.w)
        COMB(z4.z, y4.z, mb.x, mb.y)
        COMB(z4.w, y4.w, mb.z, mb.w)
    }
#undef COMB

    // ---- merge the two k-parities (lane ^ 8 flips kh only) ----
    ma.x = fmaxf(ma.x, __shfl_xor(ma.x, 8));
    ma.y = fmaxf(ma.y, __shfl_xor(ma.y, 8));
    ma.z = fmaxf(ma.z, __shfl_xor(ma.z, 8));
    ma.w = fmaxf(ma.w, __shfl_xor(ma.w, 8));
    mb.x = fmaxf(mb.x, __shfl_xor(mb.x, 8));
    mb.y = fmaxf(mb.y, __shfl_xor(mb.y, 8));
    mb.z = fmaxf(mb.z, __shfl_xor(mb.z, 8));
    mb.w = fmaxf(mb.w, __shfl_xor(mb.w, 8));

    if (kh == 0) {
        int cb = cq * 8;
        *(float2*)&tile[nl][cb]     = make_float2(ma.x, ma.y);
        *(float2*)&tile[nl][cb + 2] = make_float2(ma.z, ma.w);
        *(float2*)&tile[nl][cb + 4] = make_float2(mb.x, mb.y);
        *(float2*)&tile[nl][cb + 6] = make_float2(mb.z, mb.w);
    }
    __syncthreads();

    // ---- coalesced writeback: 64 o x 16 n ----
    #pragma unroll
    for (int r = 0; r < 4; ++r) {
        int flat = r * 256 + t;
        int o = flat >> 4, n2 = flat & 15;
        out[((size_t)b * COUT_ + o) * N_ + n0 + n2] = tile[n2][o];
    }
}

// ---------------------------------------------------------------------------
extern "C" void kernel_launch(void* const* d_in, const int* in_sizes, int n_in,
                              void* d_out, int out_size, void* d_ws, size_t ws_size,
                              hipStream_t stream) {
    const float* x    = (const float*)d_in[0];   // [B, C, N, 1]
    const int*   ei   = (const int*)  d_in[1];   // [2, B, N, K]
    const float* pos  = (const float*)d_in[2];   // [B, 3, N, 1]
    const float* W    = (const float*)d_in[3];   // [COUT, 2C]
    const float* bias = (const float*)d_in[4];   // [COUT]
    float*       out  = (float*)d_out;           // [B, COUT, N, 1]

    const size_t tabElems = (size_t)B_ * N_ * 64;            // 2.56M u16
    u16*   zbuf = (u16*)d_ws;                                // 5.12 MB
    u16*   ybuf = zbuf + tabElems;                           // 5.12 MB
    uint2* es   = (uint2*)(ybuf + tabElems);                 // 5.12 MB, 8B-aligned

    hipLaunchKernelGGL(stage1, dim3(B_ * NB1), dim3(256), 0, stream,
                       x, ei, pos, W, bias, zbuf, ybuf, es);
    hipLaunchKernelGGL(stage2, dim3(B_ * NB2), dim3(256), 0, stream,
                       es, zbuf, ybuf, out);
}